// Round 1
// baseline (1861.013 us; speedup 1.0000x reference)
//
#include <hip/hip_runtime.h>
#include <hip/hip_bf16.h>
#include <cstdint>
#include <cstddef>

#define PIX   4096
#define NFEAT 576
#define PDYN  78016
#define LATD  512
#define CATD  2048

typedef unsigned short u16;

__device__ __forceinline__ float lrelu(float v) { return v > 0.f ? v : 0.2f * v; }
__device__ __forceinline__ float bf2f(unsigned int u) {
  union { unsigned int i; float f; } c; c.i = u << 16; return c.f;
}

// ---------------- tiny utility kernels ----------------
__global__ void k_zero(float* __restrict__ p, int n) {
  int i = blockIdx.x * 256 + threadIdx.x;
  if (i < n) p[i] = 0.f;
}

// out0[b][o][p] = sum_c w_in[o][c]*x[b][c][p] + b_in[o]   (16*64*4096 threads)
__global__ void k_init_out(const float* __restrict__ x, const float* __restrict__ w_in,
                           const float* __restrict__ b_in, float* __restrict__ out) {
  int idx = blockIdx.x * 256 + threadIdx.x;
  int p = idx & 4095, o = (idx >> 12) & 63, b = idx >> 18;
  const float* xb = x + (size_t)b * 3 * PIX + p;
  out[idx] = b_in[o] + w_in[o*3+0]*xb[0] + w_in[o*3+1]*xb[PIX] + w_in[o*3+2]*xb[2*PIX];
}

// cat[b][0:512]=lat, cat[b][512:2048]=0 (freq accumulated by atomics later)
__global__ void k_cat_init(const float* __restrict__ lat, float* __restrict__ cat) {
  int idx = blockIdx.x * 256 + threadIdx.x;     // 16*2048
  int j = idx & 2047, b = idx >> 11;
  cat[idx] = (j < 512) ? lat[b*512 + j] : 0.f;
}

// ---------------- perceive + instance-norm -> xn (bf16, normalized) ----------------
__device__ __forceinline__ void feat9(const float (*ch)[65], int h, int w, float* f) {
  f[0] = ch[h][w];
#pragma unroll
  for (int di = 0; di < 4; ++di) {
    int d = 1 << di;                       // dilations 1,2,4,8
    bool hm = (h - d) >= 0, hp = (h + d) < 64;
    bool wm = (w - d) >= 0, wp = (w + d) < 64;
    float tm = (hm && wm) ? ch[h-d][w-d] : 0.f;
    float t0 =  hm        ? ch[h-d][w  ] : 0.f;
    float tp = (hm && wp) ? ch[h-d][w+d] : 0.f;
    float mm =  wm        ? ch[h  ][w-d] : 0.f;
    float mp =  wp        ? ch[h  ][w+d] : 0.f;
    float bm = (hp && wm) ? ch[h+d][w-d] : 0.f;
    float b0 =  hp        ? ch[h+d][w  ] : 0.f;
    float bp = (hp && wp) ? ch[h+d][w+d] : 0.f;
    f[1 + 2*di] = (tp - tm + 2.f*(mp - mm) + bp - bm) * 0.125f;   // Sobel X
    f[2 + 2*di] = (bm - tm + 2.f*(b0 - t0) + bp - tp) * 0.125f;   // Sobel Y
  }
}

// grid (64 channels, 16 batches), 256 threads
__global__ __launch_bounds__(256) void k_prep(const float* __restrict__ out,
                                              __hip_bfloat16* __restrict__ xn) {
  __shared__ float ch[64][65];
  __shared__ float redS[4][9], redQ[4][9];
  __shared__ float mS[9], rS[9];
  int c = blockIdx.x, b = blockIdx.y, t = threadIdx.x;
  const float* src = out + ((size_t)b * 64 + c) * PIX;
  for (int j = 0; j < 16; ++j) { int idx = t + j*256; ch[idx >> 6][idx & 63] = src[idx]; }
  __syncthreads();
  float s[9], q[9];
#pragma unroll
  for (int k = 0; k < 9; ++k) { s[k] = 0.f; q[k] = 0.f; }
  for (int j = 0; j < 16; ++j) {
    int p = t + j*256; int h = p >> 6, w = p & 63;
    float f[9]; feat9(ch, h, w, f);
#pragma unroll
    for (int k = 0; k < 9; ++k) { s[k] += f[k]; q[k] += f[k]*f[k]; }
  }
#pragma unroll
  for (int off = 32; off; off >>= 1)
#pragma unroll
    for (int k = 0; k < 9; ++k) { s[k] += __shfl_down(s[k], off, 64); q[k] += __shfl_down(q[k], off, 64); }
  int lane = t & 63, wv = t >> 6;
  if (lane == 0)
#pragma unroll
    for (int k = 0; k < 9; ++k) { redS[wv][k] = s[k]; redQ[wv][k] = q[k]; }
  __syncthreads();
  if (t < 9) {
    float ss = 0.f, qq = 0.f;
    for (int w2 = 0; w2 < 4; ++w2) { ss += redS[w2][t]; qq += redQ[w2][t]; }
    float mean = ss * (1.f/4096.f);
    float var  = qq * (1.f/4096.f) - mean*mean;
    mS[t] = mean; rS[t] = rsqrtf(var + 1e-5f);
  }
  __syncthreads();
  for (int j = 0; j < 16; ++j) {
    int p = t + j*256; int h = p >> 6, w = p & 63;
    float f[9]; feat9(ch, h, w, f);
#pragma unroll
    for (int k = 0; k < 9; ++k)
      xn[((size_t)b * NFEAT + k*64 + c) * PIX + p] = __float2bfloat16((f[k] - mS[k]) * rS[k]);
  }
}

// ---------------- dynamic-weight repack ----------------
// Wf[b][i][m]: m<64 -> k_in[m][i], m>=64 -> k_sk[m-64][i]  (k-major for LDS staging)
__global__ void k_fold(const float* __restrict__ P, float* __restrict__ Wf, int cyc) {
  int idx = blockIdx.x * 256 + threadIdx.x;        // 16*576*128
  int m = idx & 127;
  int rest = idx >> 7;
  int b = rest / 576;
  int i = rest - b * 576;
  int o = m & 63;
  size_t rowoff = (size_t)(cyc*16 + b) * PDYN;
  Wf[idx] = P[rowoff + ((m < 64) ? 0 : 41088) + (size_t)o * 576 + i];
}

__global__ void k_biascopy(const float* __restrict__ P, float* __restrict__ biasf, int cyc) {
  int idx = blockIdx.x * 256 + threadIdx.x;        // 16*128
  int b = idx >> 7, m = idx & 127, o = m & 63;
  biasf[idx] = P[(size_t)(cyc*16 + b) * PDYN + ((m < 64) ? (36864 + o) : (77952 + o))];
}

// ---------------- fused dyna_conv + k_out epilogue + freq atomics ----------------
// grid (32 pixel-tiles, 16 batches), 256 threads, M=128, Ntile=128, K=576
__global__ __launch_bounds__(256) void k_dyna(
    const float* __restrict__ Wf, const u16* __restrict__ xn,
    const float* __restrict__ biasf, const float* __restrict__ P,
    const float* __restrict__ pe, float* __restrict__ out,
    float* __restrict__ cat, int cyc) {
  __shared__ float lds[12288];                       // 48 KB, multi-purpose
  float* Wl = lds;                                   // stage: 64x128 f32
  u16*   Xl = (u16*)(lds + 8192);                    // stage: 64x128 bf16
  float* hF = lds;                                   // epi: h [128 col][64 row] xor-swizzled
  __hip_bfloat16* resB = (__hip_bfloat16*)(lds + 8192); // epi: out tile bf16 [64 o][128 col]
  float* peL = lds;                                  // freq: 24 x 132

  int t = threadIdx.x;
  int tx = t & 15, ty = t >> 4;
  int b = blockIdx.y;
  int p0 = blockIdx.x * 128;
  const float* WfB = Wf + (size_t)b * NFEAT * 128;
  const u16*   xnB = xn + (size_t)b * NFEAT * PIX + p0;

  float acc[8][8];
#pragma unroll
  for (int i = 0; i < 8; ++i)
#pragma unroll
    for (int j = 0; j < 8; ++j) acc[i][j] = 0.f;

  for (int kb = 0; kb < 9; ++kb) {
    int k0 = kb * 64;
    {
      const float4* gsrc = (const float4*)(WfB + (size_t)k0 * 128);
      float4* ldst = (float4*)Wl;
#pragma unroll
      for (int j = 0; j < 8; ++j) ldst[t + j*256] = gsrc[t + j*256];
#pragma unroll
      for (int j = 0; j < 4; ++j) {
        int c16 = t + j*256;
        int row = c16 >> 4, off = (c16 & 15) * 8;
        *(uint4*)(Xl + row*128 + off) = *(const uint4*)(xnB + (size_t)(k0 + row)*PIX + off);
      }
    }
    __syncthreads();
#pragma unroll 4
    for (int kk = 0; kk < 64; ++kk) {
      const float4 a0 = *(const float4*)(Wl + kk*128 + ty*8);
      const float4 a1 = *(const float4*)(Wl + kk*128 + ty*8 + 4);
      uint4 bx = *(const uint4*)(Xl + kk*128 + tx*8);
      float av[8] = {a0.x, a0.y, a0.z, a0.w, a1.x, a1.y, a1.z, a1.w};
      float bv[8];
      bv[0] = bf2f(bx.x & 0xffffu); bv[1] = bf2f(bx.x >> 16);
      bv[2] = bf2f(bx.y & 0xffffu); bv[3] = bf2f(bx.y >> 16);
      bv[4] = bf2f(bx.z & 0xffffu); bv[5] = bf2f(bx.z >> 16);
      bv[6] = bf2f(bx.w & 0xffffu); bv[7] = bf2f(bx.w >> 16);
#pragma unroll
      for (int i = 0; i < 8; ++i)
#pragma unroll
        for (int j = 0; j < 8; ++j) acc[i][j] += av[i] * bv[j];
    }
    __syncthreads();
  }

  // --- epilogue phase 1: h (rows 0..63) -> LDS (lrelu'd); s stays in regs of ty>=8 ---
  if (ty < 8) {
#pragma unroll
    for (int i = 0; i < 8; ++i) {
      int row = ty*8 + i;
      float bvv = biasf[b*128 + row];
      int q = row >> 2, r3 = row & 3;
#pragma unroll
      for (int j = 0; j < 8; ++j) {
        int col = tx*8 + j;
        hF[col*64 + (((q ^ (tx & 7)) << 2) | r3)] = lrelu(acc[i][j] + bvv);
      }
    }
  }
  __syncthreads();

  // --- epilogue phase 2: y = k_out @ h; res = s + y + b_out ---
  if (ty >= 8) {
    const float* Prow = P + (size_t)(cyc*16 + b) * PDYN;
#pragma unroll
    for (int i = 0; i < 8; ++i) {
      int o = (ty - 8)*8 + i;
      float bout = Prow[41024 + o];
      float bsk  = biasf[b*128 + 64 + o];
      float yv[8];
#pragma unroll
      for (int j = 0; j < 8; ++j) yv[j] = bout;
      for (int q = 0; q < 16; ++q) {
        float4 kv = *(const float4*)(Prow + 36928 + o*64 + q*4);
#pragma unroll
        for (int j = 0; j < 8; ++j) {
          int col = tx*8 + j;
          const float4 hv = *(const float4*)(hF + col*64 + ((q ^ (tx & 7)) << 2));
          yv[j] += kv.x*hv.x + kv.y*hv.y + kv.z*hv.z + kv.w*hv.w;
        }
      }
#pragma unroll
      for (int j = 0; j < 8; ++j) {
        int col = tx*8 + j;
        float res = acc[i][j] + bsk + yv[j];
        out[((size_t)b*64 + o)*PIX + p0 + col] = res;
        resB[o*128 + col] = __float2bfloat16(res);
      }
    }
  }
  __syncthreads();

  // --- epilogue phase 3: freq partials -> atomics into cat[:, 512 + o*24 + f] ---
  for (int j = t; j < 24*128; j += 256) {
    int rw = j >> 7, cl = j & 127;
    peL[rw*132 + cl] = pe[(size_t)rw * PIX + p0 + cl];
  }
  __syncthreads();
  for (int pr = t; pr < 1536; pr += 256) {
    int o = pr / 24, f = pr - o*24;
    float sum = 0.f;
    for (int col = 0; col < 128; ++col)
      sum += __bfloat162float(resB[o*128 + col]) * peL[f*132 + col];
    atomicAdd(&cat[b*CATD + 512 + o*24 + f], sum * (1.f/4096.f));
  }
}

// ---------------- generic GEMMs (f32 latent path) ----------------
// wide: C[M,N] = A[M,K]@B[K,N] + bias (M<=64 per block-row), BM=64 BN=64 BK=16
__global__ __launch_bounds__(256) void gemm_wide(
    const float* __restrict__ A, const float* __restrict__ Bm,
    float* __restrict__ C, const float* __restrict__ bias, int M, int N, int K) {
  __shared__ float As[16][68];
  __shared__ float Bs[16][64];
  int t = threadIdx.x;
  int tx = t & 15, ty = t >> 4;
  int m0 = blockIdx.y * 64, n0 = blockIdx.x * 64;
  float acc[4][4];
#pragma unroll
  for (int i = 0; i < 4; ++i)
#pragma unroll
    for (int j = 0; j < 4; ++j) acc[i][j] = 0.f;
  for (int k0 = 0; k0 < K; k0 += 16) {
#pragma unroll
    for (int j = 0; j < 4; ++j) {
      int r = (t >> 4) + j*16, c = t & 15;
      As[c][r] = (m0 + r < M) ? A[(size_t)(m0 + r)*K + k0 + c] : 0.f;
    }
#pragma unroll
    for (int j = 0; j < 4; ++j) {
      int idx = t + j*256;
      int kr = idx >> 6, nc = idx & 63;
      Bs[kr][nc] = Bm[(size_t)(k0 + kr)*N + n0 + nc];
    }
    __syncthreads();
#pragma unroll
    for (int kk = 0; kk < 16; ++kk) {
      float4 av = *(const float4*)&As[kk][ty*4];
      float4 bv = *(const float4*)&Bs[kk][tx*4];
      float a[4] = {av.x, av.y, av.z, av.w};
      float bb[4] = {bv.x, bv.y, bv.z, bv.w};
#pragma unroll
      for (int i = 0; i < 4; ++i)
#pragma unroll
        for (int j = 0; j < 4; ++j) acc[i][j] += a[i]*bb[j];
    }
    __syncthreads();
  }
#pragma unroll
  for (int i = 0; i < 4; ++i) {
    int rowg = m0 + ty*4 + i;
    if (rowg < M)
#pragma unroll
      for (int j = 0; j < 4; ++j) {
        int col = n0 + tx*4 + j;
        C[(size_t)rowg*N + col] = acc[i][j] + bias[col];
      }
  }
}

// skinny: M=16 exactly. gridDim.y = ksplit; if >1 writes partials C[ks][16][N] (no bias/act)
__global__ __launch_bounds__(256) void gemm_skinny(
    const float* __restrict__ A, const float* __restrict__ Bm,
    float* __restrict__ C, const float* __restrict__ bias,
    int N, int K, int act, int accum) {
  __shared__ float As[16][17];
  __shared__ float Bs[16][64];
  int t = threadIdx.x;
  int row = t & 15, cg = t >> 4;
  int n0 = blockIdx.x * 64;
  int ks = gridDim.y;
  int kchunk = K / ks;
  int k0base = blockIdx.y * kchunk;
  float acc[4] = {0.f, 0.f, 0.f, 0.f};
  for (int k0 = k0base; k0 < k0base + kchunk; k0 += 16) {
    { int lr = t >> 4, lc = t & 15; As[lc][lr] = A[(size_t)lr*K + k0 + lc]; }
#pragma unroll
    for (int j = 0; j < 4; ++j) {
      int idx = t + j*256;
      int kr = idx >> 6, nc = idx & 63;
      Bs[kr][nc] = Bm[(size_t)(k0 + kr)*N + n0 + nc];
    }
    __syncthreads();
#pragma unroll
    for (int kk = 0; kk < 16; ++kk) {
      float a = As[kk][row];
      float4 bv = *(const float4*)&Bs[kk][cg*4];
      acc[0] += a*bv.x; acc[1] += a*bv.y; acc[2] += a*bv.z; acc[3] += a*bv.w;
    }
    __syncthreads();
  }
  if (ks > 1) {
    float* Pp = C + (size_t)blockIdx.y * 16 * N;
#pragma unroll
    for (int j = 0; j < 4; ++j) Pp[(size_t)row*N + n0 + cg*4 + j] = acc[j];
  } else {
#pragma unroll
    for (int j = 0; j < 4; ++j) {
      int col = n0 + cg*4 + j;
      float v = acc[j] + bias[col];
      if (accum) v += C[(size_t)row*N + col];
      if (act) v = lrelu(v);
      C[(size_t)row*N + col] = v;
    }
  }
}

// C[idx] = act( bias1[col] + sum P1  (+ bias2[col] + sum P2) )
__global__ void k_reduce(float* __restrict__ C,
                         const float* __restrict__ P1, int ns1, const float* __restrict__ bias1,
                         const float* __restrict__ P2, int ns2, const float* __restrict__ bias2,
                         int nmask, int total, int act) {
  int idx = blockIdx.x * 256 + threadIdx.x;
  if (idx >= total) return;
  int col = idx & nmask;
  float v = bias1[col];
  for (int s = 0; s < ns1; ++s) v += P1[(size_t)s*total + idx];
  if (P2) { v += bias2[col]; for (int s = 0; s < ns2; ++s) v += P2[(size_t)s*total + idx]; }
  if (act) v = lrelu(v);
  C[idx] = v;
}

// ---------------- host ----------------
extern "C" void kernel_launch(void* const* d_in, const int* in_sizes, int n_in,
                              void* d_out, int out_size, void* d_ws, size_t ws_size,
                              hipStream_t stream) {
  const float* x      = (const float*)d_in[0];
  const float* inj0   = (const float*)d_in[1];
  const float* w_in   = (const float*)d_in[2];
  const float* b_in   = (const float*)d_in[3];
  const float* fl_w1  = (const float*)d_in[4];
  const float* fl_b1  = (const float*)d_in[5];
  const float* fl_w2  = (const float*)d_in[6];
  const float* fl_b2  = (const float*)d_in[7];
  const float* fl_ws  = (const float*)d_in[8];
  const float* fl_bs  = (const float*)d_in[9];
  const float* dyn_w  = (const float*)d_in[10];
  const float* dyn_b  = (const float*)d_in[11];
  const float* pe     = (const float*)d_in[12];
  const float* otl_w1 = (const float*)d_in[13];
  const float* otl_b1 = (const float*)d_in[14];
  const float* otl_w2 = (const float*)d_in[15];
  const float* otl_b2 = (const float*)d_in[16];
  const float* otl_ws = (const float*)d_in[17];
  const float* otl_bs = (const float*)d_in[18];
  const float* ltl_w  = (const float*)d_in[19];
  const float* ltl_b  = (const float*)d_in[20];
  float* outF = (float*)d_out;

  char* w = (char*)d_ws;
  float* inj_seq = (float*)(w + 0);            // 4*16*512
  float* tmpA    = (float*)(w + 131072);       // 16*2048
  float* lat     = (float*)(w + 262144);       // 16*512
  float* cat     = (float*)(w + 294912);       // 16*2048
  float* biasf   = (float*)(w + 499712);       // 16*128
  float* part1   = (float*)(w + 507904);       // 4*16*2048
  float* part2   = (float*)(w + 1032192);      // 4*16*512
  float* part3   = (float*)(w + 1163264);      // 4*16*512
  float* Wf      = (float*)(w + 1294336);      // 16*576*128
  float* Pbuf    = (float*)(w + 6012928);      // 64*78016
  float* outb    = (float*)(w + 25985024);     // 16*64*4096
  u16*   xnb     = (u16*)  (w + 42762240);     // 16*576*4096 bf16

  k_zero<<<32, 256, 0, stream>>>(lat, 16*512);
  k_init_out<<<16384, 256, 0, stream>>>(x, w_in, b_in, outb);

  // latent chain (all 4 cycles upfront), then one big dyn-param GEMM
  for (int c = 0; c < 4; ++c) {
    const float* src = (c == 0) ? inj0 : (inj_seq + (size_t)(c-1)*16*LATD);
    float* dst = inj_seq + (size_t)c*16*LATD;
    gemm_skinny<<<dim3(8,1), 256, 0, stream>>>(src,  fl_w1, tmpA, fl_b1, 512, 512, 1, 0);
    gemm_skinny<<<dim3(8,1), 256, 0, stream>>>(src,  fl_ws, dst,  fl_bs, 512, 512, 0, 0);
    gemm_skinny<<<dim3(8,1), 256, 0, stream>>>(tmpA, fl_w2, dst,  fl_b2, 512, 512, 0, 1);
  }
  gemm_wide<<<dim3(PDYN/64, 1), 256, 0, stream>>>(inj_seq, dyn_w, Pbuf, dyn_b, 64, PDYN, 512);

  for (int c = 0; c < 4; ++c) {
    k_prep<<<dim3(64,16), 256, 0, stream>>>(outb, (__hip_bfloat16*)xnb);
    k_fold<<<4608, 256, 0, stream>>>(Pbuf, Wf, c);
    k_biascopy<<<8, 256, 0, stream>>>(Pbuf, biasf, c);
    k_cat_init<<<128, 256, 0, stream>>>(lat, cat);
    k_dyna<<<dim3(32,16), 256, 0, stream>>>(Wf, xnb, biasf, Pbuf, pe, outb, cat, c);
    // otl lin_res (K-split skinny GEMMs + reduce)
    gemm_skinny<<<dim3(32,4), 256, 0, stream>>>(cat, otl_w1 + (size_t)c*CATD*CATD, part1, nullptr, 2048, 2048, 0, 0);
    k_reduce<<<128, 256, 0, stream>>>(tmpA, part1, 4, otl_b1 + c*CATD,
                                      nullptr, 0, nullptr, 2047, 16*2048, 1);
    gemm_skinny<<<dim3(8,4), 256, 0, stream>>>(cat,  otl_ws + (size_t)c*CATD*LATD, part2, nullptr, 512, 2048, 0, 0);
    gemm_skinny<<<dim3(8,4), 256, 0, stream>>>(tmpA, otl_w2 + (size_t)c*CATD*LATD, part3, nullptr, 512, 2048, 0, 0);
    k_reduce<<<32, 256, 0, stream>>>(lat, part2, 4, otl_bs + c*LATD,
                                     part3, 4, otl_b2 + c*LATD, 511, 16*512, 0);
  }
  gemm_skinny<<<dim3(8,1), 256, 0, stream>>>(lat, ltl_w, outF, ltl_b, 512, 512, 0, 0);
}

// Round 2
// 1032.945 us; speedup vs baseline: 1.8017x; 1.8017x over previous
//
#include <hip/hip_runtime.h>
#include <hip/hip_bf16.h>
#include <cstdint>
#include <cstddef>

#define PIX   4096
#define PDYN  78016
#define LATD  512
#define CATD  2048

typedef unsigned short u16;
typedef __attribute__((ext_vector_type(8))) short bf16x8;
typedef __attribute__((ext_vector_type(4))) float f32x4;
#define MFMA16(a,b,c) __builtin_amdgcn_mfma_f32_16x16x32_bf16(a,b,c,0,0,0)

__device__ __forceinline__ float lrelu(float v) { return v > 0.f ? v : 0.2f * v; }
__device__ __forceinline__ unsigned bfbits(float x) {
  __hip_bfloat16 h = __float2bfloat16(x);
  return (unsigned)*(unsigned short*)&h;
}
__device__ __forceinline__ unsigned pack2(float a, float b) {
  return bfbits(a) | (bfbits(b) << 16);
}

// ---------------- tiny utility kernels ----------------
__global__ void k_zero(float* __restrict__ p, int n) {
  int i = blockIdx.x * 256 + threadIdx.x;
  if (i < n) p[i] = 0.f;
}

__global__ void k_init_out(const float* __restrict__ x, const float* __restrict__ w_in,
                           const float* __restrict__ b_in, float* __restrict__ out) {
  int idx = blockIdx.x * 256 + threadIdx.x;
  int p = idx & 4095, o = (idx >> 12) & 63, b = idx >> 18;
  const float* xb = x + (size_t)b * 3 * PIX + p;
  out[idx] = b_in[o] + w_in[o*3+0]*xb[0] + w_in[o*3+1]*xb[PIX] + w_in[o*3+2]*xb[2*PIX];
}

__global__ void k_cat_init(const float* __restrict__ lat, float* __restrict__ cat) {
  int idx = blockIdx.x * 256 + threadIdx.x;     // 16*2048
  int j = idx & 2047, b = idx >> 11;
  cat[idx] = (j < 512) ? lat[b*512 + j] : 0.f;
}

// pe -> bf16 fragment-panel layout: peB[pt32][ft2][kc4][lane64][j8]
__global__ void k_pe(const float* __restrict__ pe, u16* __restrict__ peB) {
  int idx = blockIdx.x * 256 + threadIdx.x;     // 131072
  int j = idx & 7, lane = (idx >> 3) & 63, kc = (idx >> 9) & 3, ft = (idx >> 11) & 1, pt = idx >> 12;
  int f = ft*16 + (lane & 15);
  int p = pt*128 + kc*32 + (lane >> 4)*8 + j;
  peB[idx] = (f < 24) ? (u16)bfbits(pe[(size_t)f*PIX + p]) : (u16)0;
}

// ---------------- perceive + instance-norm -> xn (bf16, normalized) ----------------
__device__ __forceinline__ void feat9(const float (*ch)[65], int h, int w, float* f) {
  f[0] = ch[h][w];
#pragma unroll
  for (int di = 0; di < 4; ++di) {
    int d = 1 << di;
    bool hm = (h - d) >= 0, hp = (h + d) < 64;
    bool wm = (w - d) >= 0, wp = (w + d) < 64;
    float tm = (hm && wm) ? ch[h-d][w-d] : 0.f;
    float t0 =  hm        ? ch[h-d][w  ] : 0.f;
    float tp = (hm && wp) ? ch[h-d][w+d] : 0.f;
    float mm =  wm        ? ch[h  ][w-d] : 0.f;
    float mp =  wp        ? ch[h  ][w+d] : 0.f;
    float bm = (hp && wm) ? ch[h+d][w-d] : 0.f;
    float b0 =  hp        ? ch[h+d][w  ] : 0.f;
    float bp = (hp && wp) ? ch[h+d][w+d] : 0.f;
    f[1 + 2*di] = (tp - tm + 2.f*(mp - mm) + bp - bm) * 0.125f;
    f[2 + 2*di] = (bm - tm + 2.f*(b0 - t0) + bp - tp) * 0.125f;
  }
}

__global__ __launch_bounds__(256) void k_prep(const float* __restrict__ out,
                                              __hip_bfloat16* __restrict__ xn) {
  __shared__ float ch[64][65];
  __shared__ float redS[4][9], redQ[4][9];
  __shared__ float mS[9], rS[9];
  int c = blockIdx.x, b = blockIdx.y, t = threadIdx.x;
  const float* src = out + ((size_t)b * 64 + c) * PIX;
  for (int j = 0; j < 16; ++j) { int idx = t + j*256; ch[idx >> 6][idx & 63] = src[idx]; }
  __syncthreads();
  float s[9], q[9];
#pragma unroll
  for (int k = 0; k < 9; ++k) { s[k] = 0.f; q[k] = 0.f; }
  for (int j = 0; j < 16; ++j) {
    int p = t + j*256; int h = p >> 6, w = p & 63;
    float f[9]; feat9(ch, h, w, f);
#pragma unroll
    for (int k = 0; k < 9; ++k) { s[k] += f[k]; q[k] += f[k]*f[k]; }
  }
#pragma unroll
  for (int off = 32; off; off >>= 1)
#pragma unroll
    for (int k = 0; k < 9; ++k) { s[k] += __shfl_down(s[k], off, 64); q[k] += __shfl_down(q[k], off, 64); }
  int lane = t & 63, wv = t >> 6;
  if (lane == 0)
#pragma unroll
    for (int k = 0; k < 9; ++k) { redS[wv][k] = s[k]; redQ[wv][k] = q[k]; }
  __syncthreads();
  if (t < 9) {
    float ss = 0.f, qq = 0.f;
    for (int w2 = 0; w2 < 4; ++w2) { ss += redS[w2][t]; qq += redQ[w2][t]; }
    float mean = ss * (1.f/4096.f);
    float var  = qq * (1.f/4096.f) - mean*mean;
    mS[t] = mean; rS[t] = rsqrtf(var + 1e-5f);
  }
  __syncthreads();
  for (int j = 0; j < 16; ++j) {
    int p = t + j*256; int h = p >> 6, w = p & 63;
    float f[9]; feat9(ch, h, w, f);
#pragma unroll
    for (int k = 0; k < 9; ++k)
      xn[((size_t)b * 576 + k*64 + c) * PIX + p] = __float2bfloat16((f[k] - mS[k]) * rS[k]);
  }
}

// ---------------- dynamic-weight folds ----------------
// Wst[b][kg18][m128][kk32] bf16: m<64 -> k_in[m][kg*32+kk], m>=64 -> k_sk[m-64][...]
__global__ void k_fold(const float* __restrict__ P, u16* __restrict__ Wst, int cyc) {
  int idx = blockIdx.x * 256 + threadIdx.x;      // 73728 per b
  int b = blockIdx.y;
  int kk = idx & 31, m = (idx >> 5) & 127, kg = idx >> 12;
  int f = kg*32 + kk;
  const float* row = P + (size_t)(cyc*16 + b) * PDYN;
  float v = (m < 64) ? row[m*576 + f] : row[41088 + (m-64)*576 + f];
  Wst[(size_t)b * 73728 + idx] = (u16)bfbits(v);
}

// KoutF[b][ot4][kc2][lane64][j8] bf16 A-fragment layout of k_out
__global__ void k_koutfold(const float* __restrict__ P, u16* __restrict__ KoutF, int cyc) {
  int idx = blockIdx.x * 256 + threadIdx.x;      // 65536
  int j = idx & 7, lane = (idx >> 3) & 63, kc = (idx >> 9) & 1, ot = (idx >> 10) & 3, b = idx >> 12;
  int o = ot*16 + (lane & 15);
  int m = kc*32 + (lane >> 4)*8 + j;
  KoutF[idx] = (u16)bfbits(P[(size_t)(cyc*16 + b) * PDYN + 36928 + o*64 + m]);
}

// biasf[b][m]: m<64 -> b_in[m]; m>=64 -> b_sk[o] + b_out[o]
__global__ void k_biascopy(const float* __restrict__ P, float* __restrict__ biasf, int cyc) {
  int idx = blockIdx.x * 256 + threadIdx.x;      // 16*128
  int b = idx >> 7, m = idx & 127;
  const float* row = P + (size_t)(cyc*16 + b) * PDYN;
  biasf[idx] = (m < 64) ? row[36864 + m] : (row[77952 + (m-64)] + row[41024 + (m-64)]);
}

// ---------------- fused MFMA dyna_conv + k_out + freq ----------------
// grid (32 pixel-tiles, 16 batches), 256 threads (4 waves), M=128, N=128, K=576
__global__ __launch_bounds__(256) void k_dyna(
    const u16* __restrict__ Wst, const u16* __restrict__ xn,
    const u16* __restrict__ KoutF, const u16* __restrict__ peB,
    const float* __restrict__ biasf, float* __restrict__ out,
    float* __restrict__ cat) {
  __shared__ u16 lds[16384];                 // 32 KB
  u16* As = lds;                             // [128 m][64 k] swizzled; later hB; later fred(lo)
  u16* Xl = lds + 8192;                      // [128 p][64 k] swizzled; later resB [64 o][128 p]

  int t = threadIdx.x;
  int lane = t & 63, wv = t >> 6;
  int col = lane & 15, quad = lane >> 4;
  int b = blockIdx.y, p0 = blockIdx.x * 128;

  const u16* WB  = Wst + (size_t)b * 73728;
  const u16* xnB = xn  + (size_t)b * 576 * PIX + p0;

  f32x4 acc[8][2];
#pragma unroll
  for (int i = 0; i < 8; ++i) { acc[i][0] = {0.f,0.f,0.f,0.f}; acc[i][1] = {0.f,0.f,0.f,0.f}; }

  int sm = t & 127, skg = t >> 7, s7 = sm & 7;   // W staging
  int pg = t & 15, kq = t >> 4;                  // X staging

  for (int kb = 0; kb < 9; ++kb) {
    uint4 w[4];
    const uint4* wsrc = (const uint4*)(WB + (size_t)kb*8192 + sm*32 + skg*4096);
    // note: flat layout — thread t reads elems [kb*8192 + t*32, +32)
    wsrc = (const uint4*)(WB + (size_t)kb*8192 + t*32);
#pragma unroll
    for (int q = 0; q < 4; ++q) w[q] = wsrc[q];
    uint4 xr[4];
#pragma unroll
    for (int kk = 0; kk < 4; ++kk)
      xr[kk] = *(const uint4*)(xnB + (size_t)(kb*64 + kq*4 + kk)*PIX + pg*8);
    __syncthreads();   // previous iter's fragment reads done
#pragma unroll
    for (int q = 0; q < 4; ++q)
      *(uint4*)&As[sm*64 + (((skg*4 + q) ^ s7) * 8)] = w[q];
    const unsigned* xw = (const unsigned*)xr;
    unsigned pkl[8], pkh[8];
#pragma unroll
    for (int i = 0; i < 8; ++i) {
      unsigned sh = (i & 1) * 16;
      unsigned h0 = (xw[0  + (i>>1)] >> sh) & 0xffffu;
      unsigned h1 = (xw[4  + (i>>1)] >> sh) & 0xffffu;
      unsigned h2 = (xw[8  + (i>>1)] >> sh) & 0xffffu;
      unsigned h3 = (xw[12 + (i>>1)] >> sh) & 0xffffu;
      pkl[i] = h0 | (h1 << 16);
      pkh[i] = h2 | (h3 << 16);
    }
    int ch0 = kq >> 1, sub = (kq & 1) * 4;
#pragma unroll
    for (int jj = 0; jj < 8; ++jj) {
      int i = (jj + pg) & 7;
      int p = pg*8 + i;
      *(uint2*)&Xl[p*64 + ((ch0 ^ i) * 8) + sub] = make_uint2(pkl[i], pkh[i]);
    }
    __syncthreads();
#pragma unroll
    for (int kc = 0; kc < 2; ++kc) {
      bf16x8 bfr[2];
#pragma unroll
      for (int nt = 0; nt < 2; ++nt) {
        int n = wv*32 + nt*16 + col;
        bfr[nt] = *(const bf16x8*)&Xl[n*64 + (((kc*4 + quad) ^ (n & 7)) * 8)];
      }
#pragma unroll
      for (int mt = 0; mt < 8; ++mt) {
        int m = mt*16 + col;
        bf16x8 af = *(const bf16x8*)&As[m*64 + (((kc*4 + quad) ^ (m & 7)) * 8)];
        acc[mt][0] = MFMA16(af, bfr[0], acc[mt][0]);
        acc[mt][1] = MFMA16(af, bfr[1], acc[mt][1]);
      }
    }
  }
  __syncthreads();

  // --- E1: h = lrelu(acc_in + b_in) -> hB (As region), B-fragment layout [n128][m64] ---
  const float* bfB = biasf + b*128;
#pragma unroll
  for (int mt = 0; mt < 4; ++mt) {
    float bm[4];
#pragma unroll
    for (int r = 0; r < 4; ++r) bm[r] = bfB[mt*16 + quad*4 + r];
#pragma unroll
    for (int nt = 0; nt < 2; ++nt) {
      unsigned lo = pack2(lrelu(acc[mt][nt][0] + bm[0]), lrelu(acc[mt][nt][1] + bm[1]));
      unsigned hi = pack2(lrelu(acc[mt][nt][2] + bm[2]), lrelu(acc[mt][nt][3] + bm[3]));
      int nl = nt*16 + col;
      int ch = (mt*2 + (quad >> 1)) ^ (nl & 7);
      *(uint2*)&As[(wv*32 + nl)*64 + ch*8 + (quad & 1)*4] = make_uint2(lo, hi);
    }
  }
  __syncthreads();

  // --- E2: y = k_out @ h (MFMA, K=64); res = acc_sk + y + (b_sk+b_out) ---
  f32x4 yac[4][2];
#pragma unroll
  for (int i = 0; i < 4; ++i) { yac[i][0] = {0.f,0.f,0.f,0.f}; yac[i][1] = {0.f,0.f,0.f,0.f}; }
  const u16* kofB = KoutF + (size_t)b * 4096;
#pragma unroll
  for (int kc = 0; kc < 2; ++kc) {
    bf16x8 hb[2];
#pragma unroll
    for (int nt = 0; nt < 2; ++nt) {
      int nl = nt*16 + col;
      hb[nt] = *(const bf16x8*)&As[(wv*32 + nl)*64 + (((kc*4 + quad) ^ (nl & 7)) * 8)];
    }
#pragma unroll
    for (int ot = 0; ot < 4; ++ot) {
      bf16x8 ka = *(const bf16x8*)&kofB[((ot*2 + kc)*64 + lane) * 8];
      yac[ot][0] = MFMA16(ka, hb[0], yac[ot][0]);
      yac[ot][1] = MFMA16(ka, hb[1], yac[ot][1]);
    }
  }
#pragma unroll
  for (int ot = 0; ot < 4; ++ot) {
    float bo[4];
#pragma unroll
    for (int r = 0; r < 4; ++r) bo[r] = bfB[64 + ot*16 + quad*4 + r];
#pragma unroll
    for (int nt = 0; nt < 2; ++nt) {
      int pl = wv*32 + nt*16 + col;
#pragma unroll
      for (int r = 0; r < 4; ++r) {
        float rs = acc[4 + ot][nt][r] + yac[ot][nt][r] + bo[r];
        int o = ot*16 + quad*4 + r;
        out[((size_t)b*64 + o)*PIX + p0 + pl] = rs;
        Xl[o*128 + (((pl >> 3) ^ (o & 7)) * 8) + (pl & 7)] = (u16)bfbits(rs);   // resB [o][p]
      }
    }
  }
  __syncthreads();

  // --- freq: fac[o][f] += res[o][p] * pe[f][p] via MFMA, wave wv takes p-chunk wv ---
  f32x4 fac[4][2];
#pragma unroll
  for (int i = 0; i < 4; ++i) { fac[i][0] = {0.f,0.f,0.f,0.f}; fac[i][1] = {0.f,0.f,0.f,0.f}; }
  bf16x8 pb[2];
#pragma unroll
  for (int ft = 0; ft < 2; ++ft)
    pb[ft] = *(const bf16x8*)&peB[((((size_t)blockIdx.x*2 + ft)*4 + wv)*64 + lane) * 8];
#pragma unroll
  for (int mt = 0; mt < 4; ++mt) {
    int o = mt*16 + col;
    bf16x8 ar = *(const bf16x8*)&Xl[o*128 + (((wv*4 + quad) ^ (o & 7)) * 8)];
    fac[mt][0] = MFMA16(ar, pb[0], fac[mt][0]);
    fac[mt][1] = MFMA16(ar, pb[1], fac[mt][1]);
  }
  __syncthreads();
  float* fred = (float*)lds;                  // [4 wv][64 o][32 f] = 8192 f32 = 32 KB
#pragma unroll
  for (int mt = 0; mt < 4; ++mt)
#pragma unroll
    for (int ft = 0; ft < 2; ++ft)
#pragma unroll
      for (int r = 0; r < 4; ++r)
        fred[(wv*64 + mt*16 + quad*4 + r)*32 + ft*16 + col] = fac[mt][ft][r];
  __syncthreads();
  for (int pr = t; pr < 1536; pr += 256) {
    int o = pr / 24, f = pr - o*24;
    float s = fred[o*32 + f] + fred[(64 + o)*32 + f] + fred[(128 + o)*32 + f] + fred[(192 + o)*32 + f];
    atomicAdd(&cat[b*CATD + 512 + o*24 + f], s * (1.f/4096.f));
  }
}

// ---------------- generic GEMMs (f32 latent path) ----------------
__global__ __launch_bounds__(256) void gemm_wide(
    const float* __restrict__ A, const float* __restrict__ Bm,
    float* __restrict__ C, const float* __restrict__ bias, int M, int N, int K) {
  __shared__ float As[16][68];
  __shared__ float Bs[16][64];
  int t = threadIdx.x;
  int tx = t & 15, ty = t >> 4;
  int m0 = blockIdx.y * 64, n0 = blockIdx.x * 64;
  float acc[4][4];
#pragma unroll
  for (int i = 0; i < 4; ++i)
#pragma unroll
    for (int j = 0; j < 4; ++j) acc[i][j] = 0.f;
  for (int k0 = 0; k0 < K; k0 += 16) {
#pragma unroll
    for (int j = 0; j < 4; ++j) {
      int r = (t >> 4) + j*16, c = t & 15;
      As[c][r] = (m0 + r < M) ? A[(size_t)(m0 + r)*K + k0 + c] : 0.f;
    }
#pragma unroll
    for (int j = 0; j < 4; ++j) {
      int idx = t + j*256;
      int kr = idx >> 6, nc = idx & 63;
      Bs[kr][nc] = Bm[(size_t)(k0 + kr)*N + n0 + nc];
    }
    __syncthreads();
#pragma unroll
    for (int kk = 0; kk < 16; ++kk) {
      float4 av = *(const float4*)&As[kk][ty*4];
      float4 bv = *(const float4*)&Bs[kk][tx*4];
      float a[4] = {av.x, av.y, av.z, av.w};
      float bb[4] = {bv.x, bv.y, bv.z, bv.w};
#pragma unroll
      for (int i = 0; i < 4; ++i)
#pragma unroll
        for (int j = 0; j < 4; ++j) acc[i][j] += a[i]*bb[j];
    }
    __syncthreads();
  }
#pragma unroll
  for (int i = 0; i < 4; ++i) {
    int rowg = m0 + ty*4 + i;
    if (rowg < M)
#pragma unroll
      for (int j = 0; j < 4; ++j) {
        int col = n0 + tx*4 + j;
        C[(size_t)rowg*N + col] = acc[i][j] + bias[col];
      }
  }
}

// skinny M=16; gridDim.y = ksplit; ks>1 writes partials C[ks][16][N]
__global__ __launch_bounds__(256) void gemm_skinny(
    const float* __restrict__ A, const float* __restrict__ Bm,
    float* __restrict__ C, const float* __restrict__ bias,
    int N, int K, int act, int accum) {
  __shared__ float As[16][17];
  __shared__ float Bs[16][64];
  int t = threadIdx.x;
  int row = t & 15, cg = t >> 4;
  int n0 = blockIdx.x * 64;
  int ks = gridDim.y;
  int kchunk = K / ks;
  int k0base = blockIdx.y * kchunk;
  float acc[4] = {0.f, 0.f, 0.f, 0.f};
  for (int k0 = k0base; k0 < k0base + kchunk; k0 += 16) {
    { int lr = t >> 4, lc = t & 15; As[lc][lr] = A[(size_t)lr*K + k0 + lc]; }
#pragma unroll
    for (int j = 0; j < 4; ++j) {
      int idx = t + j*256;
      int kr = idx >> 6, nc = idx & 63;
      Bs[kr][nc] = Bm[(size_t)(k0 + kr)*N + n0 + nc];
    }
    __syncthreads();
#pragma unroll
    for (int kk = 0; kk < 16; ++kk) {
      float a = As[kk][row];
      float4 bv = *(const float4*)&Bs[kk][cg*4];
      acc[0] += a*bv.x; acc[1] += a*bv.y; acc[2] += a*bv.z; acc[3] += a*bv.w;
    }
    __syncthreads();
  }
  if (ks > 1) {
    float* Pp = C + (size_t)blockIdx.y * 16 * N;
#pragma unroll
    for (int j = 0; j < 4; ++j) Pp[(size_t)row*N + n0 + cg*4 + j] = acc[j];
  } else {
#pragma unroll
    for (int j = 0; j < 4; ++j) {
      int col = n0 + cg*4 + j;
      float v = acc[j] + bias[col];
      if (accum) v += C[(size_t)row*N + col];
      if (act) v = lrelu(v);
      C[(size_t)row*N + col] = v;
    }
  }
}

// C[idx] (=|+=) act( bias1[col] + sum P1 (+ bias2[col] + sum P2) )
__global__ void k_reduce(float* __restrict__ C,
                         const float* __restrict__ P1, int ns1, const float* __restrict__ bias1,
                         const float* __restrict__ P2, int ns2, const float* __restrict__ bias2,
                         int nmask, int total, int act, int accum) {
  int idx = blockIdx.x * 256 + threadIdx.x;
  if (idx >= total) return;
  int col = idx & nmask;
  float v = bias1[col];
  for (int s = 0; s < ns1; ++s) v += P1[(size_t)s*total + idx];
  if (P2) { v += bias2[col]; for (int s = 0; s < ns2; ++s) v += P2[(size_t)s*total + idx]; }
  if (act) v = lrelu(v);
  if (accum) v += C[idx];
  C[idx] = v;
}

// ---------------- host ----------------
extern "C" void kernel_launch(void* const* d_in, const int* in_sizes, int n_in,
                              void* d_out, int out_size, void* d_ws, size_t ws_size,
                              hipStream_t stream) {
  const float* x      = (const float*)d_in[0];
  const float* inj0   = (const float*)d_in[1];
  const float* w_in   = (const float*)d_in[2];
  const float* b_in   = (const float*)d_in[3];
  const float* fl_w1  = (const float*)d_in[4];
  const float* fl_b1  = (const float*)d_in[5];
  const float* fl_w2  = (const float*)d_in[6];
  const float* fl_b2  = (const float*)d_in[7];
  const float* fl_ws  = (const float*)d_in[8];
  const float* fl_bs  = (const float*)d_in[9];
  const float* dyn_w  = (const float*)d_in[10];
  const float* dyn_b  = (const float*)d_in[11];
  const float* pe     = (const float*)d_in[12];
  const float* otl_w1 = (const float*)d_in[13];
  const float* otl_b1 = (const float*)d_in[14];
  const float* otl_w2 = (const float*)d_in[15];
  const float* otl_b2 = (const float*)d_in[16];
  const float* otl_ws = (const float*)d_in[17];
  const float* otl_bs = (const float*)d_in[18];
  const float* ltl_w  = (const float*)d_in[19];
  const float* ltl_b  = (const float*)d_in[20];
  float* outF = (float*)d_out;

  char* w = (char*)d_ws;
  float* inj_seq = (float*)(w + 0);            // 4*16*512 f32         = 131072
  float* tmpA    = (float*)(w + 131072);       // 16*2048 f32          = 131072
  float* lat     = (float*)(w + 262144);       // 16*512 f32           = 32768
  float* cat     = (float*)(w + 294912);       // 16*2048 f32          = 131072
  float* biasf   = (float*)(w + 425984);       // 16*128 f32           = 8192
  float* part1   = (float*)(w + 434176);       // 16*16*2048 f32       = 2097152
  float* part2   = (float*)(w + 2531328);      // 8*16*512 f32         = 262144  (alias partL)
  float* part3   = (float*)(w + 2793472);      // 8*16*512 f32         = 262144  (alias partL2)
  u16*   Wst     = (u16*)  (w + 3055616);      // 16*73728 bf16        = 2359296
  u16*   KoutF   = (u16*)  (w + 5414912);      // 16*4096 bf16         = 131072
  u16*   peB     = (u16*)  (w + 5545984);      // 131072 bf16          = 262144
  float* Pbuf    = (float*)(w + 5808128);      // 64*78016 f32         = 19972096
  float* outb    = (float*)(w + 25780224);     // 16*64*4096 f32       = 16777216
  u16*   xnb     = (u16*)  (w + 42557440);     // 16*576*4096 bf16     = 75497472

  k_zero<<<32, 256, 0, stream>>>(lat, 16*512);
  k_init_out<<<16384, 256, 0, stream>>>(x, w_in, b_in, outb);
  k_pe<<<512, 256, 0, stream>>>(pe, peB);

  // latent chain (all 4 cycles upfront), K-split 8
  for (int c = 0; c < 4; ++c) {
    const float* src = (c == 0) ? inj0 : (inj_seq + (size_t)(c-1)*16*LATD);
    float* dst = inj_seq + (size_t)c*16*LATD;
    gemm_skinny<<<dim3(8,8), 256, 0, stream>>>(src,  fl_w1, part2, nullptr, 512, 512, 0, 0);
    k_reduce<<<32, 256, 0, stream>>>(tmpA, part2, 8, fl_b1, nullptr, 0, nullptr, 511, 8192, 1, 0);
    gemm_skinny<<<dim3(8,8), 256, 0, stream>>>(src,  fl_ws, part3, nullptr, 512, 512, 0, 0);
    k_reduce<<<32, 256, 0, stream>>>(dst, part3, 8, fl_bs, nullptr, 0, nullptr, 511, 8192, 0, 0);
    gemm_skinny<<<dim3(8,8), 256, 0, stream>>>(tmpA, fl_w2, part2, nullptr, 512, 512, 0, 0);
    k_reduce<<<32, 256, 0, stream>>>(dst, part2, 8, fl_b2, nullptr, 0, nullptr, 511, 8192, 0, 1);
  }
  gemm_wide<<<dim3(PDYN/64, 1), 256, 0, stream>>>(inj_seq, dyn_w, Pbuf, dyn_b, 64, PDYN, 512);

  for (int c = 0; c < 4; ++c) {
    k_prep<<<dim3(64,16), 256, 0, stream>>>(outb, (__hip_bfloat16*)xnb);
    k_fold<<<dim3(288,16), 256, 0, stream>>>(Pbuf, Wst, c);
    k_koutfold<<<256, 256, 0, stream>>>(Pbuf, KoutF, c);
    k_biascopy<<<8, 256, 0, stream>>>(Pbuf, biasf, c);
    k_cat_init<<<128, 256, 0, stream>>>(lat, cat);
    k_dyna<<<dim3(32,16), 256, 0, stream>>>(Wst, xnb, KoutF, peB, biasf, outb, cat);
    // otl lin_res
    gemm_skinny<<<dim3(32,16), 256, 0, stream>>>(cat, otl_w1 + (size_t)c*CATD*CATD, part1, nullptr, 2048, 2048, 0, 0);
    k_reduce<<<128, 256, 0, stream>>>(tmpA, part1, 16, otl_b1 + c*CATD,
                                      nullptr, 0, nullptr, 2047, 16*2048, 1, 0);
    gemm_skinny<<<dim3(8,8), 256, 0, stream>>>(cat,  otl_ws + (size_t)c*CATD*LATD, part2, nullptr, 512, 2048, 0, 0);
    gemm_skinny<<<dim3(8,8), 256, 0, stream>>>(tmpA, otl_w2 + (size_t)c*CATD*LATD, part3, nullptr, 512, 2048, 0, 0);
    k_reduce<<<32, 256, 0, stream>>>(lat, part2, 8, otl_bs + c*LATD,
                                     part3, 8, otl_b2 + c*LATD, 511, 16*512, 0, 0);
  }
  gemm_skinny<<<dim3(8,8), 256, 0, stream>>>(lat, ltl_w, part2, nullptr, 512, 512, 0, 0);
  k_reduce<<<32, 256, 0, stream>>>(outF, part2, 8, ltl_b, nullptr, 0, nullptr, 511, 8192, 0, 0);
}

// Round 3
// 916.809 us; speedup vs baseline: 2.0299x; 1.1267x over previous
//
#include <hip/hip_runtime.h>
#include <hip/hip_bf16.h>
#include <cstdint>
#include <cstddef>

#define PIX   4096
#define PDYN  78016
#define LATD  512
#define CATD  2048

typedef unsigned short u16;
typedef __attribute__((ext_vector_type(8))) short bf16x8;
typedef __attribute__((ext_vector_type(4))) float f32x4;
#define MFMA16(a,b,c) __builtin_amdgcn_mfma_f32_16x16x32_bf16(a,b,c,0,0,0)

__device__ __forceinline__ float lrelu(float v) { return v > 0.f ? v : 0.2f * v; }
__device__ __forceinline__ unsigned bfbits(float x) {
  __hip_bfloat16 h = __float2bfloat16(x);
  return (unsigned)*(unsigned short*)&h;
}
__device__ __forceinline__ unsigned pack2(float a, float b) {
  return bfbits(a) | (bfbits(b) << 16);
}

// ---------------- tiny utility kernels ----------------
__global__ void k_zero(float* __restrict__ p, int n) {
  int i = blockIdx.x * 256 + threadIdx.x;
  if (i < n) p[i] = 0.f;
}

__global__ void k_init_out(const float* __restrict__ x, const float* __restrict__ w_in,
                           const float* __restrict__ b_in, float* __restrict__ out) {
  int idx = blockIdx.x * 256 + threadIdx.x;
  int p = idx & 4095, o = (idx >> 12) & 63, b = idx >> 18;
  const float* xb = x + (size_t)b * 3 * PIX + p;
  out[idx] = b_in[o] + w_in[o*3+0]*xb[0] + w_in[o*3+1]*xb[PIX] + w_in[o*3+2]*xb[2*PIX];
}

__global__ void k_cat_init(const float* __restrict__ lat, float* __restrict__ cat) {
  int idx = blockIdx.x * 256 + threadIdx.x;     // 16*2048
  int j = idx & 2047, b = idx >> 11;
  cat[idx] = (j < 512) ? lat[b*512 + j] : 0.f;
}

// pe -> bf16 fragment-panel layout: peB[pt32][ft2][kc4][lane64][j8]
__global__ void k_pe(const float* __restrict__ pe, u16* __restrict__ peB) {
  int idx = blockIdx.x * 256 + threadIdx.x;     // 131072
  int j = idx & 7, lane = (idx >> 3) & 63, kc = (idx >> 9) & 3, ft = (idx >> 11) & 1, pt = idx >> 12;
  int f = ft*16 + (lane & 15);
  int p = pt*128 + kc*32 + (lane >> 4)*8 + j;
  peB[idx] = (f < 24) ? (u16)bfbits(pe[(size_t)f*PIX + p]) : (u16)0;
}

// inj_seq (64 x 512 f32) -> A-fragment bf16 panels [kb8][kc2][mt4][lane64][j8]
__global__ void k_afold(const float* __restrict__ inj_seq, u16* __restrict__ Abf) {
  int idx = blockIdx.x * 256 + threadIdx.x;     // 32768
  int j = idx & 7, lane = (idx >> 3) & 63, mt = (idx >> 9) & 3, kc = (idx >> 11) & 1, kb = idx >> 12;
  int m = mt*16 + (lane & 15);
  int k = kb*64 + kc*32 + (lane >> 4)*8 + j;
  Abf[idx] = (u16)bfbits(inj_seq[m*512 + k]);
}

// ---------------- perceive + instance-norm -> xn (bf16, normalized) ----------------
__device__ __forceinline__ void feat9(const float (*ch)[65], int h, int w, float* f) {
  f[0] = ch[h][w];
#pragma unroll
  for (int di = 0; di < 4; ++di) {
    int d = 1 << di;
    bool hm = (h - d) >= 0, hp = (h + d) < 64;
    bool wm = (w - d) >= 0, wp = (w + d) < 64;
    float tm = (hm && wm) ? ch[h-d][w-d] : 0.f;
    float t0 =  hm        ? ch[h-d][w  ] : 0.f;
    float tp = (hm && wp) ? ch[h-d][w+d] : 0.f;
    float mm =  wm        ? ch[h  ][w-d] : 0.f;
    float mp =  wp        ? ch[h  ][w+d] : 0.f;
    float bm = (hp && wm) ? ch[h+d][w-d] : 0.f;
    float b0 =  hp        ? ch[h+d][w  ] : 0.f;
    float bp = (hp && wp) ? ch[h+d][w+d] : 0.f;
    f[1 + 2*di] = (tp - tm + 2.f*(mp - mm) + bp - bm) * 0.125f;
    f[2 + 2*di] = (bm - tm + 2.f*(b0 - t0) + bp - tp) * 0.125f;
  }
}

__global__ __launch_bounds__(256) void k_prep(const float* __restrict__ out,
                                              __hip_bfloat16* __restrict__ xn) {
  __shared__ float ch[64][65];
  __shared__ float redS[4][9], redQ[4][9];
  __shared__ float mS[9], rS[9];
  int c = blockIdx.x, b = blockIdx.y, t = threadIdx.x;
  const float* src = out + ((size_t)b * 64 + c) * PIX;
  for (int j = 0; j < 16; ++j) { int idx = t + j*256; ch[idx >> 6][idx & 63] = src[idx]; }
  __syncthreads();
  float s[9], q[9];
#pragma unroll
  for (int k = 0; k < 9; ++k) { s[k] = 0.f; q[k] = 0.f; }
  for (int j = 0; j < 16; ++j) {
    int p = t + j*256; int h = p >> 6, w = p & 63;
    float f[9]; feat9(ch, h, w, f);
#pragma unroll
    for (int k = 0; k < 9; ++k) { s[k] += f[k]; q[k] += f[k]*f[k]; }
  }
#pragma unroll
  for (int off = 32; off; off >>= 1)
#pragma unroll
    for (int k = 0; k < 9; ++k) { s[k] += __shfl_down(s[k], off, 64); q[k] += __shfl_down(q[k], off, 64); }
  int lane = t & 63, wv = t >> 6;
  if (lane == 0)
#pragma unroll
    for (int k = 0; k < 9; ++k) { redS[wv][k] = s[k]; redQ[wv][k] = q[k]; }
  __syncthreads();
  if (t < 9) {
    float ss = 0.f, qq = 0.f;
    for (int w2 = 0; w2 < 4; ++w2) { ss += redS[w2][t]; qq += redQ[w2][t]; }
    float mean = ss * (1.f/4096.f);
    float var  = qq * (1.f/4096.f) - mean*mean;
    mS[t] = mean; rS[t] = rsqrtf(var + 1e-5f);
  }
  __syncthreads();
  for (int j = 0; j < 16; ++j) {
    int p = t + j*256; int h = p >> 6, w = p & 63;
    float f[9]; feat9(ch, h, w, f);
#pragma unroll
    for (int k = 0; k < 9; ++k)
      xn[((size_t)b * 576 + k*64 + c) * PIX + p] = __float2bfloat16((f[k] - mS[k]) * rS[k]);
  }
}

// ---------------- P-GEMM: (64x512)@(512x78016) MFMA + folded scatter epilogue -------
// grid 610 blocks x 256 thr. A pre-folded bf16 (Abf). B = dyn_w f32, converted inline.
// Epilogue scatters each P element directly into Wst4/KoutF4/biasf4 (all 4 cycles).
__global__ __launch_bounds__(256) void k_pgemm(
    const u16* __restrict__ Abf, const float* __restrict__ Bw,
    const float* __restrict__ bias, u16* __restrict__ Wst4,
    u16* __restrict__ KoutF4, float* __restrict__ biasf4) {
  __shared__ u16 Xl[128 * 64];                  // 16 KB, swizzled B panel
  int t = threadIdx.x;
  int lane = t & 63, wv = t >> 6;
  int col = lane & 15, quad = lane >> 4;
  int n0 = blockIdx.x * 128;
  int pg = t & 15, kq = t >> 4;                 // staging: 16 n-groups x (16 kq x 4 k)

  f32x4 acc[4][2];
#pragma unroll
  for (int i = 0; i < 4; ++i) { acc[i][0] = {0.f,0.f,0.f,0.f}; acc[i][1] = {0.f,0.f,0.f,0.f}; }

  bool vld = (n0 + pg*8) < PDYN;                // whole 8-col group validity (PDYN%8==0)

  for (int kb = 0; kb < 8; ++kb) {
    float br[4][8];
#pragma unroll
    for (int kk = 0; kk < 4; ++kk) {
      const float* src = Bw + (size_t)(kb*64 + kq*4 + kk)*PDYN + n0 + pg*8;
      float4 a0 = vld ? *(const float4*)src       : float4{0.f,0.f,0.f,0.f};
      float4 a1 = vld ? *(const float4*)(src + 4) : float4{0.f,0.f,0.f,0.f};
      br[kk][0]=a0.x; br[kk][1]=a0.y; br[kk][2]=a0.z; br[kk][3]=a0.w;
      br[kk][4]=a1.x; br[kk][5]=a1.y; br[kk][6]=a1.z; br[kk][7]=a1.w;
    }
    __syncthreads();
    int ch0 = kq >> 1, sub = (kq & 1) * 4;
#pragma unroll
    for (int jj = 0; jj < 8; ++jj) {
      int i = (jj + pg) & 7;
      unsigned lo = pack2(br[0][i], br[1][i]);
      unsigned hi = pack2(br[2][i], br[3][i]);
      int p = pg*8 + i;
      *(uint2*)&Xl[p*64 + ((ch0 ^ i) * 8) + sub] = make_uint2(lo, hi);
    }
    __syncthreads();
#pragma unroll
    for (int kc = 0; kc < 2; ++kc) {
      bf16x8 bfr[2];
#pragma unroll
      for (int nt = 0; nt < 2; ++nt) {
        int n = wv*32 + nt*16 + col;
        bfr[nt] = *(const bf16x8*)&Xl[n*64 + (((kc*4 + quad) ^ (n & 7)) * 8)];
      }
#pragma unroll
      for (int mt = 0; mt < 4; ++mt) {
        bf16x8 af = *(const bf16x8*)&Abf[(((kb*2 + kc)*4 + mt)*64 + lane) * 8];
        acc[mt][0] = MFMA16(af, bfr[0], acc[mt][0]);
        acc[mt][1] = MFMA16(af, bfr[1], acc[mt][1]);
      }
    }
  }

  // scatter epilogue: P[prow=cyc*16+b][pcol] -> folded layouts
#pragma unroll
  for (int nt = 0; nt < 2; ++nt) {
    int pcol = n0 + wv*32 + nt*16 + col;
    if (pcol >= PDYN) continue;
    float bb = bias[pcol];
#pragma unroll
    for (int mt = 0; mt < 4; ++mt) {
#pragma unroll
      for (int r = 0; r < 4; ++r) {
        int lb = mt*16 + quad*4 + r;           // latent row = cyc*16+b
        float v = acc[mt][nt][r] + bb;
        if (pcol < 36864) {                     // k_in[o][f]
          int o = pcol / 576, f = pcol - o*576;
          Wst4[(size_t)lb*73728 + (f>>5)*4096 + o*32 + (f&31)] = (u16)bfbits(v);
        } else if (pcol < 36928) {              // b_in
          biasf4[lb*192 + (pcol - 36864)] = v;
        } else if (pcol < 41024) {              // k_out[o][m]
          int q = pcol - 36928; int o = q >> 6, m = q & 63;
          int lk = ((m & 31) >> 3)*16 + (o & 15);
          KoutF4[(size_t)lb*4096 + (((o>>4)*2 + (m>>5))*64 + lk)*8 + (m & 7)] = (u16)bfbits(v);
        } else if (pcol < 41088) {              // b_out
          biasf4[lb*192 + 64 + (pcol - 41024)] = v;
        } else if (pcol < 77952) {              // k_sk[o][f]
          int q = pcol - 41088; int o = q / 576, f = q - o*576;
          Wst4[(size_t)lb*73728 + (f>>5)*4096 + (64 + o)*32 + (f&31)] = (u16)bfbits(v);
        } else {                                // b_sk
          biasf4[lb*192 + 128 + (pcol - 77952)] = v;
        }
      }
    }
  }
}

// ---------------- fused MFMA dyna_conv + k_out + freq ----------------
__global__ __launch_bounds__(256) void k_dyna(
    const u16* __restrict__ Wst4, const u16* __restrict__ xn,
    const u16* __restrict__ KoutF4, const u16* __restrict__ peB,
    const float* __restrict__ biasf4, float* __restrict__ out,
    float* __restrict__ cat, int cyc) {
  __shared__ u16 lds[16384];                 // 32 KB
  u16* As = lds;
  u16* Xl = lds + 8192;

  int t = threadIdx.x;
  int lane = t & 63, wv = t >> 6;
  int col = lane & 15, quad = lane >> 4;
  int b = blockIdx.y, p0 = blockIdx.x * 128;

  const u16* WB  = Wst4 + (size_t)(cyc*16 + b) * 73728;
  const u16* xnB = xn  + (size_t)b * 576 * PIX + p0;

  f32x4 acc[8][2];
#pragma unroll
  for (int i = 0; i < 8; ++i) { acc[i][0] = {0.f,0.f,0.f,0.f}; acc[i][1] = {0.f,0.f,0.f,0.f}; }

  int sm = t & 127, skg = t >> 7, s7 = sm & 7;
  int pg = t & 15, kq = t >> 4;
  (void)skg; (void)sm; (void)s7;

  for (int kb = 0; kb < 9; ++kb) {
    uint4 w[4];
    const uint4* wsrc = (const uint4*)(WB + (size_t)kb*8192 + t*32);
#pragma unroll
    for (int q = 0; q < 4; ++q) w[q] = wsrc[q];
    uint4 xr[4];
#pragma unroll
    for (int kk = 0; kk < 4; ++kk)
      xr[kk] = *(const uint4*)(xnB + (size_t)(kb*64 + kq*4 + kk)*PIX + pg*8);
    __syncthreads();
    {
      int m = t & 127, kg = t >> 7, m7 = m & 7;
#pragma unroll
      for (int q = 0; q < 4; ++q)
        *(uint4*)&As[m*64 + (((kg*4 + q) ^ m7) * 8)] = w[q];
    }
    const unsigned* xw = (const unsigned*)xr;
    unsigned pkl[8], pkh[8];
#pragma unroll
    for (int i = 0; i < 8; ++i) {
      unsigned sh = (i & 1) * 16;
      unsigned h0 = (xw[0  + (i>>1)] >> sh) & 0xffffu;
      unsigned h1 = (xw[4  + (i>>1)] >> sh) & 0xffffu;
      unsigned h2 = (xw[8  + (i>>1)] >> sh) & 0xffffu;
      unsigned h3 = (xw[12 + (i>>1)] >> sh) & 0xffffu;
      pkl[i] = h0 | (h1 << 16);
      pkh[i] = h2 | (h3 << 16);
    }
    int ch0 = kq >> 1, sub = (kq & 1) * 4;
#pragma unroll
    for (int jj = 0; jj < 8; ++jj) {
      int i = (jj + pg) & 7;
      int p = pg*8 + i;
      *(uint2*)&Xl[p*64 + ((ch0 ^ i) * 8) + sub] = make_uint2(pkl[i], pkh[i]);
    }
    __syncthreads();
#pragma unroll
    for (int kc = 0; kc < 2; ++kc) {
      bf16x8 bfr[2];
#pragma unroll
      for (int nt = 0; nt < 2; ++nt) {
        int n = wv*32 + nt*16 + col;
        bfr[nt] = *(const bf16x8*)&Xl[n*64 + (((kc*4 + quad) ^ (n & 7)) * 8)];
      }
#pragma unroll
      for (int mt = 0; mt < 8; ++mt) {
        int m = mt*16 + col;
        bf16x8 af = *(const bf16x8*)&As[m*64 + (((kc*4 + quad) ^ (m & 7)) * 8)];
        acc[mt][0] = MFMA16(af, bfr[0], acc[mt][0]);
        acc[mt][1] = MFMA16(af, bfr[1], acc[mt][1]);
      }
    }
  }
  __syncthreads();

  // E1: h = lrelu(acc_in + b_in) -> B-fragment layout in As
  const float* bfB = biasf4 + (size_t)(cyc*16 + b) * 192;
#pragma unroll
  for (int mt = 0; mt < 4; ++mt) {
    float bm[4];
#pragma unroll
    for (int r = 0; r < 4; ++r) bm[r] = bfB[mt*16 + quad*4 + r];
#pragma unroll
    for (int nt = 0; nt < 2; ++nt) {
      unsigned lo = pack2(lrelu(acc[mt][nt][0] + bm[0]), lrelu(acc[mt][nt][1] + bm[1]));
      unsigned hi = pack2(lrelu(acc[mt][nt][2] + bm[2]), lrelu(acc[mt][nt][3] + bm[3]));
      int nl = nt*16 + col;
      int ch = (mt*2 + (quad >> 1)) ^ (nl & 7);
      *(uint2*)&As[(wv*32 + nl)*64 + ch*8 + (quad & 1)*4] = make_uint2(lo, hi);
    }
  }
  __syncthreads();

  // E2: y = k_out @ h; res = acc_sk + y + (b_sk + b_out)
  f32x4 yac[4][2];
#pragma unroll
  for (int i = 0; i < 4; ++i) { yac[i][0] = {0.f,0.f,0.f,0.f}; yac[i][1] = {0.f,0.f,0.f,0.f}; }
  const u16* kofB = KoutF4 + (size_t)(cyc*16 + b) * 4096;
#pragma unroll
  for (int kc = 0; kc < 2; ++kc) {
    bf16x8 hb[2];
#pragma unroll
    for (int nt = 0; nt < 2; ++nt) {
      int nl = nt*16 + col;
      hb[nt] = *(const bf16x8*)&As[(wv*32 + nl)*64 + (((kc*4 + quad) ^ (nl & 7)) * 8)];
    }
#pragma unroll
    for (int ot = 0; ot < 4; ++ot) {
      bf16x8 ka = *(const bf16x8*)&kofB[((ot*2 + kc)*64 + lane) * 8];
      yac[ot][0] = MFMA16(ka, hb[0], yac[ot][0]);
      yac[ot][1] = MFMA16(ka, hb[1], yac[ot][1]);
    }
  }
#pragma unroll
  for (int ot = 0; ot < 4; ++ot) {
    float bo[4];
#pragma unroll
    for (int r = 0; r < 4; ++r) {
      int o = ot*16 + quad*4 + r;
      bo[r] = bfB[64 + o] + bfB[128 + o];
    }
#pragma unroll
    for (int nt = 0; nt < 2; ++nt) {
      int pl = wv*32 + nt*16 + col;
#pragma unroll
      for (int r = 0; r < 4; ++r) {
        float rs = acc[4 + ot][nt][r] + yac[ot][nt][r] + bo[r];
        int o = ot*16 + quad*4 + r;
        out[((size_t)b*64 + o)*PIX + p0 + pl] = rs;
        Xl[o*128 + (((pl >> 3) ^ (o & 7)) * 8) + (pl & 7)] = (u16)bfbits(rs);
      }
    }
  }
  __syncthreads();

  // freq via MFMA
  f32x4 fac[4][2];
#pragma unroll
  for (int i = 0; i < 4; ++i) { fac[i][0] = {0.f,0.f,0.f,0.f}; fac[i][1] = {0.f,0.f,0.f,0.f}; }
  bf16x8 pb[2];
#pragma unroll
  for (int ft = 0; ft < 2; ++ft)
    pb[ft] = *(const bf16x8*)&peB[((((size_t)blockIdx.x*2 + ft)*4 + wv)*64 + lane) * 8];
#pragma unroll
  for (int mt = 0; mt < 4; ++mt) {
    int o = mt*16 + col;
    bf16x8 ar = *(const bf16x8*)&Xl[o*128 + (((wv*4 + quad) ^ (o & 7)) * 8)];
    fac[mt][0] = MFMA16(ar, pb[0], fac[mt][0]);
    fac[mt][1] = MFMA16(ar, pb[1], fac[mt][1]);
  }
  __syncthreads();
  float* fred = (float*)lds;
#pragma unroll
  for (int mt = 0; mt < 4; ++mt)
#pragma unroll
    for (int ft = 0; ft < 2; ++ft)
#pragma unroll
      for (int r = 0; r < 4; ++r)
        fred[(wv*64 + mt*16 + quad*4 + r)*32 + ft*16 + col] = fac[mt][ft][r];
  __syncthreads();
  for (int pr = t; pr < 1536; pr += 256) {
    int o = pr / 24, f = pr - o*24;
    float s = fred[o*32 + f] + fred[(64 + o)*32 + f] + fred[(128 + o)*32 + f] + fred[(192 + o)*32 + f];
    atomicAdd(&cat[b*CATD + 512 + o*24 + f], s * (1.f/4096.f));
  }
}

// ---------------- skinny f32 GEMMs (latent path), partial-only + dual-B ----------------
__global__ __launch_bounds__(256) void gemm_skinny(
    const float* __restrict__ A, const float* __restrict__ Bm,
    float* __restrict__ C, int N, int K) {
  __shared__ float As[16][17];
  __shared__ float Bs[16][64];
  int t = threadIdx.x;
  int row = t & 15, cg = t >> 4;
  int n0 = blockIdx.x * 64;
  int ks = gridDim.y;
  int kchunk = K / ks;
  int k0base = blockIdx.y * kchunk;
  float acc[4] = {0.f, 0.f, 0.f, 0.f};
  for (int k0 = k0base; k0 < k0base + kchunk; k0 += 16) {
    { int lr = t >> 4, lc = t & 15; As[lc][lr] = A[(size_t)lr*K + k0 + lc]; }
#pragma unroll
    for (int j = 0; j < 4; ++j) {
      int idx = t + j*256;
      int kr = idx >> 6, nc = idx & 63;
      Bs[kr][nc] = Bm[(size_t)(k0 + kr)*N + n0 + nc];
    }
    __syncthreads();
#pragma unroll
    for (int kk = 0; kk < 16; ++kk) {
      float a = As[kk][row];
      float4 bv = *(const float4*)&Bs[kk][cg*4];
      acc[0] += a*bv.x; acc[1] += a*bv.y; acc[2] += a*bv.z; acc[3] += a*bv.w;
    }
    __syncthreads();
  }
  float* Pp = C + (size_t)blockIdx.y * 16 * N;
#pragma unroll
  for (int j = 0; j < 4; ++j) Pp[(size_t)row*N + n0 + cg*4 + j] = acc[j];
}

__global__ __launch_bounds__(256) void gemm_skinny2(
    const float* __restrict__ A,
    const float* __restrict__ B1, float* __restrict__ C1, int N1, int tiles1,
    const float* __restrict__ B2, float* __restrict__ C2, int N2, int K) {
  __shared__ float As[16][17];
  __shared__ float Bs[16][64];
  int bx = blockIdx.x;
  const float* Bm; float* C; int N, n0;
  if (bx < tiles1) { Bm = B1; C = C1; N = N1; n0 = bx*64; }
  else             { Bm = B2; C = C2; N = N2; n0 = (bx - tiles1)*64; }
  int t = threadIdx.x;
  int row = t & 15, cg = t >> 4;
  int ks = gridDim.y;
  int kchunk = K / ks;
  int k0base = blockIdx.y * kchunk;
  float acc[4] = {0.f, 0.f, 0.f, 0.f};
  for (int k0 = k0base; k0 < k0base + kchunk; k0 += 16) {
    { int lr = t >> 4, lc = t & 15; As[lc][lr] = A[(size_t)lr*K + k0 + lc]; }
#pragma unroll
    for (int j = 0; j < 4; ++j) {
      int idx = t + j*256;
      int kr = idx >> 6, nc = idx & 63;
      Bs[kr][nc] = Bm[(size_t)(k0 + kr)*N + n0 + nc];
    }
    __syncthreads();
#pragma unroll
    for (int kk = 0; kk < 16; ++kk) {
      float a = As[kk][row];
      float4 bv = *(const float4*)&Bs[kk][cg*4];
      acc[0] += a*bv.x; acc[1] += a*bv.y; acc[2] += a*bv.z; acc[3] += a*bv.w;
    }
    __syncthreads();
  }
  float* Pp = C + (size_t)blockIdx.y * 16 * N;
#pragma unroll
  for (int j = 0; j < 4; ++j) Pp[(size_t)row*N + n0 + cg*4 + j] = acc[j];
}

// C[idx] (=|+=) act( bias1[col] + sum P1 (+ bias2[col] + sum P2) )
__global__ void k_reduce(float* __restrict__ C,
                         const float* __restrict__ P1, int ns1, const float* __restrict__ bias1,
                         const float* __restrict__ P2, int ns2, const float* __restrict__ bias2,
                         int nmask, int total, int act, int accum) {
  int idx = blockIdx.x * 256 + threadIdx.x;
  if (idx >= total) return;
  int col = idx & nmask;
  float v = bias1[col];
  for (int s = 0; s < ns1; ++s) v += P1[(size_t)s*total + idx];
  if (P2) { v += bias2[col]; for (int s = 0; s < ns2; ++s) v += P2[(size_t)s*total + idx]; }
  if (act) v = lrelu(v);
  if (accum) v += C[idx];
  C[idx] = v;
}

// ---------------- host ----------------
extern "C" void kernel_launch(void* const* d_in, const int* in_sizes, int n_in,
                              void* d_out, int out_size, void* d_ws, size_t ws_size,
                              hipStream_t stream) {
  const float* x      = (const float*)d_in[0];
  const float* inj0   = (const float*)d_in[1];
  const float* w_in   = (const float*)d_in[2];
  const float* b_in   = (const float*)d_in[3];
  const float* fl_w1  = (const float*)d_in[4];
  const float* fl_b1  = (const float*)d_in[5];
  const float* fl_w2  = (const float*)d_in[6];
  const float* fl_b2  = (const float*)d_in[7];
  const float* fl_ws  = (const float*)d_in[8];
  const float* fl_bs  = (const float*)d_in[9];
  const float* dyn_w  = (const float*)d_in[10];
  const float* dyn_b  = (const float*)d_in[11];
  const float* pe     = (const float*)d_in[12];
  const float* otl_w1 = (const float*)d_in[13];
  const float* otl_b1 = (const float*)d_in[14];
  const float* otl_w2 = (const float*)d_in[15];
  const float* otl_b2 = (const float*)d_in[16];
  const float* otl_ws = (const float*)d_in[17];
  const float* otl_bs = (const float*)d_in[18];
  const float* ltl_w  = (const float*)d_in[19];
  const float* ltl_b  = (const float*)d_in[20];
  float* outF = (float*)d_out;

  char* w = (char*)d_ws;
  float* inj_seq = (float*)(w + 0);            // 131072
  float* tmpA    = (float*)(w + 131072);       // 131072
  float* lat     = (float*)(w + 262144);       // 32768
  float* cat     = (float*)(w + 294912);       // 131072
  float* biasf4  = (float*)(w + 425984);       // 64*192*4 = 49152
  float* part1   = (float*)(w + 475136);       // 16*16*2048*4 = 2097152
  float* part2   = (float*)(w + 2572288);      // 16*16*512*4 = 524288
  float* part3   = (float*)(w + 3096576);      // 524288
  u16*   Wst4    = (u16*)  (w + 3620864);      // 64*73728*2 = 9437184
  u16*   KoutF4  = (u16*)  (w + 13058048);     // 64*4096*2 = 524288
  u16*   Abf     = (u16*)  (w + 13582336);     // 32768*2 = 65536
  u16*   peB     = (u16*)  (w + 13647872);     // 262144
  float* outb    = (float*)(w + 13910016);     // 16777216
  u16*   xnb     = (u16*)  (w + 30687232);     // 75497472

  k_zero<<<32, 256, 0, stream>>>(lat, 16*512);
  k_init_out<<<16384, 256, 0, stream>>>(x, w_in, b_in, outb);
  k_pe<<<512, 256, 0, stream>>>(pe, peB);

  // latent chain (all 4 cycles upfront): 4 launches/cycle
  for (int c = 0; c < 4; ++c) {
    const float* src = (c == 0) ? inj0 : (inj_seq + (size_t)(c-1)*16*LATD);
    float* dst = inj_seq + (size_t)c*16*LATD;
    gemm_skinny2<<<dim3(16,8), 256, 0, stream>>>(src, fl_w1, part2, 512, 8, fl_ws, part3, 512, 512);
    k_reduce<<<32, 256, 0, stream>>>(tmpA, part2, 8, fl_b1, nullptr, 0, nullptr, 511, 8192, 1, 0);
    gemm_skinny<<<dim3(8,8), 256, 0, stream>>>(tmpA, fl_w2, part2, 512, 512);
    k_reduce<<<32, 256, 0, stream>>>(dst, part3, 8, fl_bs, part2, 8, fl_b2, 511, 8192, 0, 0);
  }
  k_afold<<<128, 256, 0, stream>>>(inj_seq, Abf);
  k_pgemm<<<610, 256, 0, stream>>>(Abf, dyn_w, dyn_b, Wst4, KoutF4, biasf4);

  for (int c = 0; c < 4; ++c) {
    k_prep<<<dim3(64,16), 256, 0, stream>>>(outb, (__hip_bfloat16*)xnb);
    k_cat_init<<<128, 256, 0, stream>>>(lat, cat);
    k_dyna<<<dim3(32,16), 256, 0, stream>>>(Wst4, xnb, KoutF4, peB, biasf4, outb, cat, c);
    gemm_skinny2<<<dim3(40,16), 256, 0, stream>>>(cat, otl_w1 + (size_t)c*CATD*CATD, part1, 2048, 32,
                                                  otl_ws + (size_t)c*CATD*LATD, part3, 512, 2048);
    k_reduce<<<128, 256, 0, stream>>>(tmpA, part1, 16, otl_b1 + c*CATD,
                                      nullptr, 0, nullptr, 2047, 16*2048, 1, 0);
    gemm_skinny<<<dim3(8,16), 256, 0, stream>>>(tmpA, otl_w2 + (size_t)c*CATD*LATD, part2, 512, 2048);
    k_reduce<<<32, 256, 0, stream>>>(lat, part3, 16, otl_bs + c*LATD,
                                     part2, 16, otl_b2 + c*LATD, 511, 16*512, 0, 0);
  }
  gemm_skinny<<<dim3(8,8), 256, 0, stream>>>(lat, ltl_w, part2, 512, 512);
  k_reduce<<<32, 256, 0, stream>>>(outF, part2, 8, ltl_b, nullptr, 0, nullptr, 511, 8192, 0, 0);
}